// Round 9
// baseline (305.258 us; speedup 1.0000x reference)
//
#include <hip/hip_runtime.h>

#define CLAMP_THR 0.9999999f

typedef float f4  __attribute__((ext_vector_type(4)));                // 16B-aligned
typedef float f4a __attribute__((ext_vector_type(4), aligned(4)));    // 4B-aligned

__global__ void zero_loss_kernel(float* out) {
    if (threadIdx.x == 0) out[0] = 0.0f;
}

__device__ __forceinline__ void lds_fence() {
    // order ds_write -> ds_read within a wave, no block barrier needed
    __builtin_amdgcn_wave_barrier();
    asm volatile("s_waitcnt lgkmcnt(0)" ::: "memory");
    __builtin_amdgcn_wave_barrier();
}

// Compute one element from 27 in-register inputs; write gradients; return loss.
__device__ __forceinline__ float compute_store(
    const float R[9], const float A[9], const float B[9],
    float* __restrict__ o1, float* __restrict__ o2)
{
    // M = R_rel^T @ R_w2c2 ; M[i][k] = sum_j R[j][i]*A[j][k]
    float M[9];
    #pragma unroll
    for (int i = 0; i < 3; ++i)
        #pragma unroll
        for (int k = 0; k < 3; ++k)
            M[3 * i + k] = R[i]     * A[k]
                         + R[3 + i] * A[3 + k]
                         + R[6 + i] * A[6 + k];
    float tr = 0.0f;
    #pragma unroll
    for (int j = 0; j < 9; ++j) tr += M[j] * B[j];

    const float cosv = 0.5f * (tr - 1.0f);
    const float cosc = fminf(fmaxf(cosv, -CLAMP_THR), CLAMP_THR);
    const float g = (fabsf(cosv) < CLAMP_THR)
                      ? (-0.5f / sqrtf(1.0f - cosc * cosc))
                      : 0.0f;

    f4a s;
    s.x = g*M[0]; s.y = g*M[1]; s.z = g*M[2]; s.w = g*M[3];
    *(f4a*)(o1) = s;
    s.x = g*M[4]; s.y = g*M[5]; s.z = g*M[6]; s.w = g*M[7];
    *(f4a*)(o1 + 4) = s;
    o1[8] = g*M[8];

    float D[9];
    #pragma unroll
    for (int i = 0; i < 3; ++i)
        #pragma unroll
        for (int k = 0; k < 3; ++k)
            D[3 * i + k] = g * (R[3 * i]     * B[k]
                              + R[3 * i + 1] * B[3 + k]
                              + R[3 * i + 2] * B[6 + k]);
    s.x = D[0]; s.y = D[1]; s.z = D[2]; s.w = D[3];
    *(f4a*)(o2) = s;
    s.x = D[4]; s.y = D[5]; s.z = D[6]; s.w = D[7];
    *(f4a*)(o2 + 4) = s;
    o2[8] = D[8];

    return acosf(cosc);
}

// Wave-private LDS staging: coalesced 16B-aligned loads, wave-level fence only.
template<bool USE_WS>
__global__ __launch_bounds__(256) void geodesic_wls_kernel(
    const float* __restrict__ Rrel,   // [N,3,3]
    const float* __restrict__ Rw1,    // [N,3,3]  R_w2c1
    const float* __restrict__ Rw2,    // [N,3,3]  R_w2c2
    float* __restrict__ out,          // [1 + 9N + 9N]
    float* __restrict__ ws,           // per-wave loss partials (USE_WS)
    int n)
{
    __shared__ float lds[4][3][576];  // [wave][array][64 elems * 9] = 27648 B

    const int t    = threadIdx.x;
    const int lane = t & 63;
    const int w    = t >> 6;
    const int E0   = (blockIdx.x * 4 + w) * 64;   // wave's first element

    float local_loss = 0.0f;
    float* __restrict__ out1 = out + 1;
    float* __restrict__ out2 = out + 1 + (size_t)n * 9;

    if (E0 + 64 <= n) {
        // ---- coalesced loads: wave base = E0*36 bytes, 16B-aligned ----
        const size_t gbase = (size_t)E0 * 9;
        const f4* __restrict__ gA = (const f4*)(Rrel + gbase);
        const f4* __restrict__ gB = (const f4*)(Rw2  + gbase);
        const f4* __restrict__ gC = (const f4*)(Rw1  + gbase);
        const bool third = (lane < 16);           // 144 granules = 2.25 waves

        f4 ra0 = gA[lane], rb0 = gB[lane], rc0 = gC[lane];
        f4 ra1 = gA[64 + lane], rb1 = gB[64 + lane], rc1 = gC[64 + lane];
        f4 ra2, rb2, rc2;
        if (third) { ra2 = gA[128 + lane]; rb2 = gB[128 + lane]; rc2 = gC[128 + lane]; }

        f4* __restrict__ sA = (f4*)lds[w][0];
        f4* __restrict__ sB = (f4*)lds[w][1];
        f4* __restrict__ sC = (f4*)lds[w][2];
        sA[lane] = ra0;       sB[lane] = rb0;       sC[lane] = rc0;
        sA[64 + lane] = ra1;  sB[64 + lane] = rb1;  sC[64 + lane] = rc1;
        if (third) { sA[128 + lane] = ra2; sB[128 + lane] = rb2; sC[128 + lane] = rc2; }
        lds_fence();

        // ---- per-thread fragment read (stride 9 -> 2 lanes/bank, free) ----
        const float* __restrict__ fA = lds[w][0] + 9 * lane;
        const float* __restrict__ fB = lds[w][1] + 9 * lane;
        const float* __restrict__ fC = lds[w][2] + 9 * lane;
        float R[9], A[9], B[9];
        #pragma unroll
        for (int j = 0; j < 9; ++j) { R[j] = fA[j]; A[j] = fB[j]; B[j] = fC[j]; }

        const size_t b = (size_t)(E0 + lane) * 9;
        local_loss = compute_store(R, A, B, out1 + b, out2 + b);
    } else if (E0 + lane < n) {
        // ---- tail wave: direct divergent loads (R6 path) ----
        const size_t b = (size_t)(E0 + lane) * 9;
        float R[9], A[9], B[9];
        f4a v;
        v = *(const f4a*)(Rrel + b);     R[0]=v.x; R[1]=v.y; R[2]=v.z; R[3]=v.w;
        v = *(const f4a*)(Rrel + b + 4); R[4]=v.x; R[5]=v.y; R[6]=v.z; R[7]=v.w;
        R[8] = Rrel[b + 8];
        v = *(const f4a*)(Rw2 + b);      A[0]=v.x; A[1]=v.y; A[2]=v.z; A[3]=v.w;
        v = *(const f4a*)(Rw2 + b + 4);  A[4]=v.x; A[5]=v.y; A[6]=v.z; A[7]=v.w;
        A[8] = Rw2[b + 8];
        v = *(const f4a*)(Rw1 + b);      B[0]=v.x; B[1]=v.y; B[2]=v.z; B[3]=v.w;
        v = *(const f4a*)(Rw1 + b + 4);  B[4]=v.x; B[5]=v.y; B[6]=v.z; B[7]=v.w;
        B[8] = Rw1[b + 8];
        local_loss = compute_store(R, A, B, out1 + b, out2 + b);
    }

    // ---- loss: wave shuffle reduce -> per-wave partial (no block barrier) ----
    #pragma unroll
    for (int off = 32; off > 0; off >>= 1)
        local_loss += __shfl_down(local_loss, off, 64);
    if (lane == 0) {
        const int gw = blockIdx.x * 4 + w;
        if (USE_WS) ws[gw] = local_loss;
        else if (local_loss != 0.0f) atomicAdd(out, local_loss);
    }
}

__global__ __launch_bounds__(1024) void reduce_loss_kernel(
    const float* __restrict__ ws, int nw, float* __restrict__ out)
{
    __shared__ float wsum[16];
    const int t = threadIdx.x;
    float s = 0.0f;
    for (int i = t; i < nw; i += 1024) s += ws[i];
    #pragma unroll
    for (int off = 32; off > 0; off >>= 1)
        s += __shfl_down(s, off, 64);
    if ((t & 63) == 0) wsum[t >> 6] = s;
    __syncthreads();
    if (t == 0) {
        float tot = 0.0f;
        #pragma unroll
        for (int i = 0; i < 16; ++i) tot += wsum[i];
        out[0] = tot;
    }
}

extern "C" void kernel_launch(void* const* d_in, const int* in_sizes, int n_in,
                              void* d_out, int out_size, void* d_ws, size_t ws_size,
                              hipStream_t stream) {
    const float* Rrel = (const float*)d_in[0];
    const float* Rw1  = (const float*)d_in[1];
    const float* Rw2  = (const float*)d_in[2];
    float* out = (float*)d_out;
    const int n  = in_sizes[0] / 9;
    const int nb = (n + 255) / 256;
    const int nw = nb * 4;

    if (ws_size >= (size_t)nw * sizeof(float)) {
        geodesic_wls_kernel<true><<<nb, 256, 0, stream>>>(
            Rrel, Rw1, Rw2, out, (float*)d_ws, n);
        reduce_loss_kernel<<<1, 1024, 0, stream>>>((const float*)d_ws, nw, out);
    } else {
        zero_loss_kernel<<<1, 64, 0, stream>>>(out);
        geodesic_wls_kernel<false><<<nb, 256, 0, stream>>>(
            Rrel, Rw1, Rw2, out, nullptr, n);
    }
}